// Round 1
// baseline (825.346 us; speedup 1.0000x reference)
//
#include <hip/hip_runtime.h>

#define BATCH 8192
#define LEN   4096
#define CHUNK 128          // steps per chunk
#define NCHUNK 32
#define TPB   256

__device__ __forceinline__ float sigm(float v) { return 1.0f / (1.0f + expf(-v)); }

// One Holt-Winters step in rotated-seasonal form. s0 is the slot about to be
// read; after the step everything shifts left and the new seasonal goes to s6.
__device__ __forceinline__ void hw_step(float xv, float a, float b, float g,
    float& l, float& tr,
    float& s0, float& s1, float& s2, float& s3, float& s4, float& s5, float& s6,
    float& o0, float& o1, float& o2)
{
    float prev = s0;
    float nl = a * (xv - prev) + (1.0f - a) * (l + tr);
    float nt = b * (nl - l) + (1.0f - b) * tr;
    float ns = g * (xv - nl) + (1.0f - g) * prev;
    l = nl; tr = nt;
    s0 = s1; s1 = s2; s2 = s3; s3 = s4; s4 = s5; s5 = s6; s6 = ns;
    o0 = nl; o1 = nt; o2 = ns;
}

__device__ __forceinline__ void hw_step_n(float xv, float a, float b, float g,
    float& l, float& tr,
    float& s0, float& s1, float& s2, float& s3, float& s4, float& s5, float& s6)
{
    float d0, d1, d2;
    hw_step(xv, a, b, g, l, tr, s0, s1, s2, s3, s4, s5, s6, d0, d1, d2);
}

// ---------------------------------------------------------------------------
// Kernel 1: build M (9x9 one-step transition in rotated form), then M^127 and
// M^128 via repeated squaring. wsM[0..80] = M^127, wsM[81..161] = M^128.
// ---------------------------------------------------------------------------
__global__ void hw_setup(const float* __restrict__ alpha, const float* __restrict__ beta,
                         const float* __restrict__ gamma, float* __restrict__ wsM)
{
    __shared__ float pw[8][81];       // pw[k] = M^(2^k), row-major
    __shared__ float q[81], tmp[81];
    int t = threadIdx.x;
    float a = sigm(alpha[0]), b = sigm(beta[0]), g = sigm(gamma[0]);

    if (t < 9) {
        // column t of M = one step applied to basis vector e_t with x = 0
        float z[9];
        #pragma unroll
        for (int i = 0; i < 9; i++) z[i] = (i == t) ? 1.0f : 0.0f;
        float l = z[0], tr = z[1];
        float s0 = z[2], s1 = z[3], s2 = z[4], s3 = z[5], s4 = z[6], s5 = z[7], s6 = z[8];
        hw_step_n(0.0f, a, b, g, l, tr, s0, s1, s2, s3, s4, s5, s6);
        float zn[9] = {l, tr, s0, s1, s2, s3, s4, s5, s6};
        #pragma unroll
        for (int i = 0; i < 9; i++) pw[0][i * 9 + t] = zn[i];
    }
    __syncthreads();
    for (int k = 1; k < 8; k++) {
        if (t < 81) {
            int i = t / 9, j = t % 9;
            float acc = 0.0f;
            #pragma unroll
            for (int m = 0; m < 9; m++) acc += pw[k - 1][i * 9 + m] * pw[k - 1][m * 9 + j];
            pw[k][t] = acc;
        }
        __syncthreads();
    }
    // M^127 = M^64 * M^32 * ... * M^1  (running product)
    if (t < 81) q[t] = pw[0][t];
    __syncthreads();
    for (int k = 1; k < 7; k++) {
        if (t < 81) {
            int i = t / 9, j = t % 9;
            float acc = 0.0f;
            #pragma unroll
            for (int m = 0; m < 9; m++) acc += pw[k][i * 9 + m] * q[m * 9 + j];
            tmp[t] = acc;
        }
        __syncthreads();
        if (t < 81) q[t] = tmp[t];
        __syncthreads();
    }
    if (t < 81) { wsM[t] = q[t]; wsM[81 + t] = pw[7][t]; }
}

// ---------------------------------------------------------------------------
// Kernel 2: per (row, chunk j=0..30), run the chunk recurrence from ZERO state
// -> x-contribution vector c_j (valid by linearity). Stored at slot j:
// wsC[(j*9 + k)*BATCH + r]  (r-fast => coalesced).
// Chunk 0 = steps t=1..127; chunk j>=1 = steps t=j*128 .. j*128+127.
// ---------------------------------------------------------------------------
__global__ __launch_bounds__(TPB) void hw_partial(const float* __restrict__ x,
    const float* __restrict__ ab, const float* __restrict__ bb, const float* __restrict__ gb,
    float* __restrict__ wsC)
{
    int j = blockIdx.x >> 5;                       // 32 blocks per chunk
    int r = ((blockIdx.x & 31) << 8) + threadIdx.x;
    float a = sigm(ab[0]), b = sigm(bb[0]), g = sigm(gb[0]);
    const float4* xv4 = (const float4*)(x + (size_t)r * LEN + (size_t)j * CHUNK);

    float l = 0.f, tr = 0.f;
    float s0 = 0.f, s1 = 0.f, s2 = 0.f, s3 = 0.f, s4 = 0.f, s5 = 0.f, s6 = 0.f;

    if (j == 0) {
        float4 v = xv4[0];
        hw_step_n(v.y, a, b, g, l, tr, s0, s1, s2, s3, s4, s5, s6);
        hw_step_n(v.z, a, b, g, l, tr, s0, s1, s2, s3, s4, s5, s6);
        hw_step_n(v.w, a, b, g, l, tr, s0, s1, s2, s3, s4, s5, s6);
        #pragma unroll
        for (int i = 1; i < 32; i++) {
            float4 u = xv4[i];
            hw_step_n(u.x, a, b, g, l, tr, s0, s1, s2, s3, s4, s5, s6);
            hw_step_n(u.y, a, b, g, l, tr, s0, s1, s2, s3, s4, s5, s6);
            hw_step_n(u.z, a, b, g, l, tr, s0, s1, s2, s3, s4, s5, s6);
            hw_step_n(u.w, a, b, g, l, tr, s0, s1, s2, s3, s4, s5, s6);
        }
    } else {
        #pragma unroll
        for (int i = 0; i < 32; i++) {
            float4 u = xv4[i];
            hw_step_n(u.x, a, b, g, l, tr, s0, s1, s2, s3, s4, s5, s6);
            hw_step_n(u.y, a, b, g, l, tr, s0, s1, s2, s3, s4, s5, s6);
            hw_step_n(u.z, a, b, g, l, tr, s0, s1, s2, s3, s4, s5, s6);
            hw_step_n(u.w, a, b, g, l, tr, s0, s1, s2, s3, s4, s5, s6);
        }
    }
    float z[9] = {l, tr, s0, s1, s2, s3, s4, s5, s6};
    #pragma unroll
    for (int k = 0; k < 9; k++) wsC[((size_t)j * 9 + k) * BATCH + r] = z[k];
}

// ---------------------------------------------------------------------------
// Kernel 3: per row, chain chunk-start states:
//   z_start[0] = z0 (from x[r][0..6]), stored at slot 31
//   z_start[j] = Mpow * z_start[j-1] + c_{j-1}, stored IN PLACE at slot j-1
// Mpow = M^127 for j==1 (chunk0 has 127 steps), else M^128.
// ---------------------------------------------------------------------------
__global__ __launch_bounds__(TPB) void hw_combine(const float* __restrict__ x,
    float* __restrict__ wsC, const float* __restrict__ wsM)
{
    __shared__ float M127[81], M128[81];
    if (threadIdx.x < 81) { M127[threadIdx.x] = wsM[threadIdx.x]; M128[threadIdx.x] = wsM[81 + threadIdx.x]; }
    __syncthreads();
    int r = blockIdx.x * TPB + threadIdx.x;
    const float* xr = x + (size_t)r * LEN;

    float x0 = xr[0];
    float z[9];
    z[0] = x0;              // level0
    z[1] = xr[1] - x0;      // trend0
    // rotated seasonal: s[k] = buf0[(1+k)%7];  buf0[k] = x[k]-x0, buf0[0] = 0
    z[2] = xr[1] - x0; z[3] = xr[2] - x0; z[4] = xr[3] - x0;
    z[5] = xr[4] - x0; z[6] = xr[5] - x0; z[7] = xr[6] - x0; z[8] = 0.0f;

    #pragma unroll
    for (int k = 0; k < 9; k++) wsC[((size_t)31 * 9 + k) * BATCH + r] = z[k];

    for (int j = 1; j < NCHUNK; j++) {
        const float* Mm = (j == 1) ? M127 : M128;
        float zn[9];
        #pragma unroll
        for (int i = 0; i < 9; i++) {
            float acc = 0.0f;
            #pragma unroll
            for (int m = 0; m < 9; m++) acc += Mm[i * 9 + m] * z[m];
            zn[i] = acc + wsC[((size_t)(j - 1) * 9 + i) * BATCH + r];
        }
        #pragma unroll
        for (int i = 0; i < 9; i++) { wsC[((size_t)(j - 1) * 9 + i) * BATCH + r] = zn[i]; z[i] = zn[i]; }
    }
}

// ---------------------------------------------------------------------------
// Kernel 4: per (row, chunk), load true start state, re-run chunk, write
// (level, trend, seasonal) triples. Chunk 0 also writes the t=0 initial row.
// ---------------------------------------------------------------------------
__global__ __launch_bounds__(TPB) void hw_final(const float* __restrict__ x,
    const float* __restrict__ ab, const float* __restrict__ bb, const float* __restrict__ gb,
    const float* __restrict__ wsC, float* __restrict__ out)
{
    int j = blockIdx.x >> 5;
    int r = ((blockIdx.x & 31) << 8) + threadIdx.x;
    float a = sigm(ab[0]), b = sigm(bb[0]), g = sigm(gb[0]);

    int slot = (j == 0) ? 31 : (j - 1);
    float z[9];
    #pragma unroll
    for (int k = 0; k < 9; k++) z[k] = wsC[((size_t)slot * 9 + k) * BATCH + r];
    float l = z[0], tr = z[1];
    float s0 = z[2], s1 = z[3], s2 = z[4], s3 = z[5], s4 = z[6], s5 = z[7], s6 = z[8];

    const float4* xv4 = (const float4*)(x + (size_t)r * LEN + (size_t)j * CHUNK);
    float4* ov = (float4*)(out + ((size_t)r * LEN + (size_t)j * CHUNK) * 3);

    if (j == 0) {
        float4 v = xv4[0];
        float o[12];
        o[0] = l; o[1] = tr; o[2] = s6;     // t=0 initial row (seas0 = 0)
        hw_step(v.y, a, b, g, l, tr, s0, s1, s2, s3, s4, s5, s6, o[3], o[4], o[5]);
        hw_step(v.z, a, b, g, l, tr, s0, s1, s2, s3, s4, s5, s6, o[6], o[7], o[8]);
        hw_step(v.w, a, b, g, l, tr, s0, s1, s2, s3, s4, s5, s6, o[9], o[10], o[11]);
        ov[0] = make_float4(o[0], o[1], o[2], o[3]);
        ov[1] = make_float4(o[4], o[5], o[6], o[7]);
        ov[2] = make_float4(o[8], o[9], o[10], o[11]);
        #pragma unroll
        for (int i = 1; i < 32; i++) {
            float4 u = xv4[i];
            float p[12];
            hw_step(u.x, a, b, g, l, tr, s0, s1, s2, s3, s4, s5, s6, p[0], p[1], p[2]);
            hw_step(u.y, a, b, g, l, tr, s0, s1, s2, s3, s4, s5, s6, p[3], p[4], p[5]);
            hw_step(u.z, a, b, g, l, tr, s0, s1, s2, s3, s4, s5, s6, p[6], p[7], p[8]);
            hw_step(u.w, a, b, g, l, tr, s0, s1, s2, s3, s4, s5, s6, p[9], p[10], p[11]);
            ov[i * 3 + 0] = make_float4(p[0], p[1], p[2], p[3]);
            ov[i * 3 + 1] = make_float4(p[4], p[5], p[6], p[7]);
            ov[i * 3 + 2] = make_float4(p[8], p[9], p[10], p[11]);
        }
    } else {
        #pragma unroll
        for (int i = 0; i < 32; i++) {
            float4 u = xv4[i];
            float p[12];
            hw_step(u.x, a, b, g, l, tr, s0, s1, s2, s3, s4, s5, s6, p[0], p[1], p[2]);
            hw_step(u.y, a, b, g, l, tr, s0, s1, s2, s3, s4, s5, s6, p[3], p[4], p[5]);
            hw_step(u.z, a, b, g, l, tr, s0, s1, s2, s3, s4, s5, s6, p[6], p[7], p[8]);
            hw_step(u.w, a, b, g, l, tr, s0, s1, s2, s3, s4, s5, s6, p[9], p[10], p[11]);
            ov[i * 3 + 0] = make_float4(p[0], p[1], p[2], p[3]);
            ov[i * 3 + 1] = make_float4(p[4], p[5], p[6], p[7]);
            ov[i * 3 + 2] = make_float4(p[8], p[9], p[10], p[11]);
        }
    }
}

extern "C" void kernel_launch(void* const* d_in, const int* in_sizes, int n_in,
                              void* d_out, int out_size, void* d_ws, size_t ws_size,
                              hipStream_t stream)
{
    const float* x     = (const float*)d_in[0];
    const float* alpha = (const float*)d_in[1];
    const float* beta  = (const float*)d_in[2];
    const float* gamma = (const float*)d_in[3];
    float* out = (float*)d_out;

    float* wsM = (float*)d_ws;        // 162 floats used, 256 reserved
    float* wsC = wsM + 256;           // 32 * 9 * 8192 floats (~9.4 MB)

    hipLaunchKernelGGL(hw_setup,   dim3(1),       dim3(128), 0, stream, alpha, beta, gamma, wsM);
    hipLaunchKernelGGL(hw_partial, dim3(31 * 32), dim3(TPB), 0, stream, x, alpha, beta, gamma, wsC);
    hipLaunchKernelGGL(hw_combine, dim3(32),      dim3(TPB), 0, stream, x, wsC, wsM);
    hipLaunchKernelGGL(hw_final,   dim3(32 * 32), dim3(TPB), 0, stream, x, alpha, beta, gamma, wsC, out);
}